// Round 5
// baseline (54.982 us; speedup 1.0000x reference)
//
#include <hip/hip_runtime.h>

using f16x8 = __attribute__((ext_vector_type(8))) _Float16;
using f16x4 = __attribute__((ext_vector_type(4))) _Float16;
using f32x4 = __attribute__((ext_vector_type(4))) float;

#define T_SEQ 2048
#define D_MODEL 512
#define NH 8
#define HD 64
#define NB 2
#define M_ROWS (NB * T_SEQ)   // 4096

// async global->LDS, 16B per lane. LDS dest must be wave-uniform base;
// HW adds lane*16. Source is per-lane.
#define GLOAD_LDS16(g, l)                                              \
  __builtin_amdgcn_global_load_lds(                                    \
      (const __attribute__((address_space(1))) void*)(g),              \
      (__attribute__((address_space(3))) void*)(l), 16, 0, 0)

// ---------------------------------------------------------------- converts
// fused: blocks [0,2048) convert x -> fp16; blocks [2048,3072) transpose-
// convert the 4 weight matrices and copy qkv biases.
__global__ __launch_bounds__(256) void cvt_all(
    const float* __restrict__ x, const float* __restrict__ wq,
    const float* __restrict__ wk, const float* __restrict__ wv,
    const float* __restrict__ wo, const float* __restrict__ bq,
    const float* __restrict__ bk, const float* __restrict__ bv,
    _Float16* __restrict__ xh, _Float16* __restrict__ wT,
    float* __restrict__ bias3) {
  int bid = blockIdx.x;
  int i = threadIdx.x;
  if (bid < 2048) {
    int idx = (bid * 256 + i) * 4;
    float4 v = *(const float4*)(x + idx);
    f16x4 h;
    h[0] = (_Float16)v.x; h[1] = (_Float16)v.y;
    h[2] = (_Float16)v.z; h[3] = (_Float16)v.w;
    *(f16x4*)(xh + idx) = h;
    return;
  }
  bid -= 2048;
  const int z = bid >> 8;
  const int by = (bid >> 4) & 15;
  const int bx = bid & 15;
  const float* w = z == 0 ? wq : z == 1 ? wk : z == 2 ? wv : wo;
  __shared__ float t[32][33];
  int r0 = by * 32, c0 = bx * 32;
#pragma unroll
  for (int p = 0; p < 4; ++p) {
    int e = p * 256 + i;
    int row = e >> 5, col = e & 31;
    t[row][col] = w[(size_t)(r0 + row) * D_MODEL + c0 + col];
  }
  __syncthreads();
  _Float16* o = wT + (size_t)z * D_MODEL * D_MODEL;
#pragma unroll
  for (int p = 0; p < 4; ++p) {
    int e = p * 256 + i;
    int orow = e >> 5, ocol = e & 31;
    o[(size_t)(c0 + orow) * D_MODEL + r0 + ocol] = (_Float16)t[ocol][orow];
  }
  if (bx == 0 && by == 0 && z < 3) {
    const float* bb = z == 0 ? bq : z == 1 ? bk : bv;
#pragma unroll
    for (int p = 0; p < 2; ++p)
      bias3[z * D_MODEL + p * 256 + i] = bb[p * 256 + i];
  }
}

// ---------------------------------------------------------------- QKV GEMM
// C[m][n] = sum_k A[m][k]*Bt[n][k] + bias[n]; 2-phase dbuf, gload_lds staging.
__global__ __launch_bounds__(256) void gemm_qkv(
    const _Float16* __restrict__ A, const _Float16* __restrict__ BtBase,
    const float* __restrict__ biasBase, _Float16* __restrict__ outBase) {
  constexpr int NT = D_MODEL / 32;      // 16 K-steps
  const int z = blockIdx.z;
  const _Float16* Bt = BtBase + (size_t)z * D_MODEL * D_MODEL;
  const float* bias = biasBase + z * D_MODEL;
  const int m0 = blockIdx.y * 128;
  const int n0 = blockIdx.x * 128;
  __shared__ _Float16 At[2][128 * 32];
  __shared__ _Float16 Bts[2][128 * 32];
  const int tid = threadIdx.x;
  const int l = tid & 63;
  const int wv = tid >> 6;
  const int wm = wv >> 1, wn = wv & 1;
  const int r16 = l & 15, g4 = l >> 4;
  f32x4 acc[4][4] = {};

  auto stage = [&](int bb, int k0) {
#pragma unroll
    for (int cc = 0; cc < 2; ++cc) {
      int c = tid + cc * 256;
      int row = c >> 2, part = c & 3;
      GLOAD_LDS16(&A[(size_t)(m0 + row) * D_MODEL + k0 + part * 8],
                  &At[bb][(c - l) * 8]);
      GLOAD_LDS16(&Bt[(size_t)(n0 + row) * D_MODEL + k0 + part * 8],
                  &Bts[bb][(c - l) * 8]);
    }
  };
  auto compute = [&](int bb) {
    f16x8 a[4], b[4];
#pragma unroll
    for (int mf = 0; mf < 4; ++mf)
      a[mf] = *(const f16x8*)&At[bb][(wm * 64 + mf * 16 + r16) * 32 + g4 * 8];
#pragma unroll
    for (int nf = 0; nf < 4; ++nf)
      b[nf] = *(const f16x8*)&Bts[bb][(wn * 64 + nf * 16 + r16) * 32 + g4 * 8];
#pragma unroll
    for (int mf = 0; mf < 4; ++mf)
#pragma unroll
      for (int nf = 0; nf < 4; ++nf)
        acc[mf][nf] = __builtin_amdgcn_mfma_f32_16x16x32_f16(
            a[mf], b[nf], acc[mf][nf], 0, 0, 0);
  };

  stage(0, 0);
  __syncthreads();
#pragma unroll
  for (int t = 0; t < NT; ++t) {
    if (t + 1 < NT) stage((t + 1) & 1, (t + 1) * 32);
    compute(t & 1);
    __syncthreads();
  }
#pragma unroll
  for (int mf = 0; mf < 4; ++mf) {
#pragma unroll
    for (int nf = 0; nf < 4; ++nf) {
      int col = n0 + wn * 64 + nf * 16 + r16;
      float bs = bias[col];
#pragma unroll
      for (int r = 0; r < 4; ++r) {
        int rowi = m0 + wm * 64 + mf * 16 + g4 * 4 + r;
        outBase[(size_t)z * M_ROWS * D_MODEL + (size_t)rowi * D_MODEL + col] =
            (_Float16)(acc[mf][nf][r] + bs);
      }
    }
  }
}

// ---------------------------------------------------------------- fused attn + out-GEMM
// one block per (16-query tile, batch). 4 waves, each owns 2 heads.
// keys j=0..79 map to t = t0-32+j; window for query q: j in [q, q+64].
// OOB keys = zero vector (score 0 in softmax denom = reference zero-pad).
// Attn phase is fully wave-local (no barriers): K/Q fragments direct from
// global; V reg-transposed into a per-wave LDS slice; P per-wave; O written
// to the shared att tile (16 x 512, stride 520). One barrier, then the
// out-GEMM: A from att LDS, B (woT) direct from global, C = 16x512 + bo.
__global__ __launch_bounds__(256) void attn_out(
    const _Float16* __restrict__ Q, const _Float16* __restrict__ K,
    const _Float16* __restrict__ V, const _Float16* __restrict__ woT,
    const float* __restrict__ bo, float* __restrict__ out) {
  constexpr int VT_H = 64 * 96;   // per-wave Vt halfs
  constexpr int PS_H = 16 * 96;   // per-wave Ps halfs
  constexpr int ATT_STRIDE = 520;
  __shared__ __align__(16) _Float16 smem[4 * VT_H + 4 * PS_H + 16 * ATT_STRIDE];
  const int t0 = blockIdx.x * 16;
  const int b = blockIdx.y;
  const int k0 = t0 - 32;
  const int tid = threadIdx.x;
  const int l = tid & 63;
  const int wv = tid >> 6;
  const int r16 = l & 15, g4 = l >> 4;
  _Float16* Vt = smem + wv * VT_H;
  _Float16* Ps = smem + 4 * VT_H + wv * PS_H;
  _Float16* attL = smem + 4 * VT_H + 4 * PS_H;

  // zero the padded tails once (avoid poisoned-LDS NaN x 0 in MFMA)
  {
    f16x8 zz = {};
    *(f16x8*)&Vt[l * 96 + 80] = zz;
    *(f16x8*)&Vt[l * 96 + 88] = zz;
    if (l < 32) *(f16x8*)&Ps[(l >> 1) * 96 + 80 + (l & 1) * 8] = zz;
  }

  for (int hi = 0; hi < 2; ++hi) {
    const int h = wv * 2 + hi;
    const size_t cb = (size_t)h * HD;
    // stage V transposed: Vt[d][key], keys 0..79, guarded
#pragma unroll
    for (int j = 0; j < 10; ++j) {
      int c = l + j * 64;             // [0, 640)
      int key = c >> 3, part = c & 7;
      int t = k0 + key;
      f16x8 v = {};
      if (t >= 0 && t < T_SEQ)
        v = *(const f16x8*)&V[(size_t)(b * T_SEQ + t) * D_MODEL + cb +
                              part * 8];
#pragma unroll
      for (int jj = 0; jj < 8; ++jj) Vt[(part * 8 + jj) * 96 + key] = v[jj];
    }
    // S = Q K^T : 16 queries x 80 keys, K=64
    f32x4 s[5] = {};
#pragma unroll
    for (int ks = 0; ks < 2; ++ks) {
      f16x8 a = *(const f16x8*)&Q[(size_t)(b * T_SEQ + t0 + r16) * D_MODEL +
                                  cb + ks * 32 + g4 * 8];
#pragma unroll
      for (int nf = 0; nf < 5; ++nf) {
        int t = k0 + nf * 16 + r16;
        f16x8 bb = {};
        if (t >= 0 && t < T_SEQ)
          bb = *(const f16x8*)&K[(size_t)(b * T_SEQ + t) * D_MODEL + cb +
                                 ks * 32 + g4 * 8];
        s[nf] = __builtin_amdgcn_mfma_f32_16x16x32_f16(a, bb, s[nf], 0, 0, 0);
      }
    }
    // softmax rows q = g4*4 + r, cols j = nf*16 + r16; window j in [q, q+64]
#pragma unroll
    for (int r = 0; r < 4; ++r) {
      int q = g4 * 4 + r;
      float vals[5];
      float m = -1e30f;
#pragma unroll
      for (int nf = 0; nf < 5; ++nf) {
        int j = nf * 16 + r16;
        bool in = (j >= q) && (j <= q + 64);
        float sv = in ? s[nf][r] * 0.125f : -1e30f;
        vals[nf] = sv;
        m = fmaxf(m, sv);
      }
#pragma unroll
      for (int off = 1; off < 16; off <<= 1)
        m = fmaxf(m, __shfl_xor(m, off, 64));
      float e[5];
      float sum = 0.f;
#pragma unroll
      for (int nf = 0; nf < 5; ++nf) {
        float ev = (vals[nf] > -1e29f) ? __expf(vals[nf] - m) : 0.f;
        e[nf] = ev;
        sum += ev;
      }
#pragma unroll
      for (int off = 1; off < 16; off <<= 1) sum += __shfl_xor(sum, off, 64);
      float inv = 1.f / sum;
#pragma unroll
      for (int nf = 0; nf < 5; ++nf)
        Ps[q * 96 + nf * 16 + r16] = (_Float16)(e[nf] * inv);
    }
    // O = P V : 16 q x 64 d, K = 96 (keys 80..95 have P = 0)
    f32x4 o[4] = {};
#pragma unroll
    for (int ks = 0; ks < 3; ++ks) {
      f16x8 a = *(const f16x8*)&Ps[r16 * 96 + ks * 32 + g4 * 8];
#pragma unroll
      for (int nf = 0; nf < 4; ++nf) {
        f16x8 bb = *(const f16x8*)&Vt[(nf * 16 + r16) * 96 + ks * 32 + g4 * 8];
        o[nf] = __builtin_amdgcn_mfma_f32_16x16x32_f16(a, bb, o[nf], 0, 0, 0);
      }
    }
#pragma unroll
    for (int nf = 0; nf < 4; ++nf)
#pragma unroll
      for (int r = 0; r < 4; ++r)
        attL[(g4 * 4 + r) * ATT_STRIDE + h * HD + nf * 16 + r16] =
            (_Float16)o[nf][r];
  }
  __syncthreads();
  // out-GEMM: C[16][512] = att @ woT^T(+bo); wave wv owns cols [wv*128,+128)
  f32x4 acc[8] = {};
  const int nbase = wv * 128;
  for (int kk = 0; kk < 16; ++kk) {
    f16x8 a = *(const f16x8*)&attL[r16 * ATT_STRIDE + kk * 32 + g4 * 8];
    f16x8 bfr[8];
#pragma unroll
    for (int nf = 0; nf < 8; ++nf)
      bfr[nf] = *(const f16x8*)&woT[(size_t)(nbase + nf * 16 + r16) * D_MODEL +
                                    kk * 32 + g4 * 8];
#pragma unroll
    for (int nf = 0; nf < 8; ++nf)
      acc[nf] = __builtin_amdgcn_mfma_f32_16x16x32_f16(a, bfr[nf], acc[nf],
                                                       0, 0, 0);
  }
#pragma unroll
  for (int nf = 0; nf < 8; ++nf) {
    int col = nbase + nf * 16 + r16;
    float bs = bo[col];
#pragma unroll
    for (int r = 0; r < 4; ++r)
      out[(size_t)(b * T_SEQ + t0 + g4 * 4 + r) * D_MODEL + col] =
          acc[nf][r] + bs;
  }
}

// ---------------------------------------------------------------- launch
extern "C" void kernel_launch(void* const* d_in, const int* in_sizes, int n_in,
                              void* d_out, int out_size, void* d_ws,
                              size_t ws_size, hipStream_t stream) {
  const float* x = (const float*)d_in[0];
  const float* wq = (const float*)d_in[1];
  const float* bq = (const float*)d_in[2];
  const float* wk = (const float*)d_in[3];
  const float* bk = (const float*)d_in[4];
  const float* wv = (const float*)d_in[5];
  const float* bv = (const float*)d_in[6];
  const float* wo = (const float*)d_in[7];
  const float* bo = (const float*)d_in[8];

  char* ws = (char*)d_ws;
  _Float16* xh = (_Float16*)(ws);                    // 4 MB
  _Float16* wT = (_Float16*)(ws + (4 << 20));        // 2 MB
  float* bias3 = (float*)(ws + (6 << 20));           // 6 KB
  _Float16* QKV = (_Float16*)(ws + (6 << 20) + (64 << 10));  // 12 MB

  cvt_all<<<3072, 256, 0, stream>>>(x, wq, wk, wv, wo, bq, bk, bv, xh, wT,
                                    bias3);
  gemm_qkv<<<dim3(4, 32, 3), 256, 0, stream>>>(xh, wT, bias3, QKV);
  const _Float16* Qm = QKV;
  const _Float16* Km = QKV + (size_t)M_ROWS * D_MODEL;
  const _Float16* Vm = Km + (size_t)M_ROWS * D_MODEL;
  attn_out<<<dim3(T_SEQ / 16, NB), 256, 0, stream>>>(
      Qm, Km, Vm, wT + (size_t)3 * D_MODEL * D_MODEL, bo, (float*)d_out);
}

// Round 6
// 44.097 us; speedup vs baseline: 1.2469x; 1.2469x over previous
//
#include <hip/hip_runtime.h>

using f16x8 = __attribute__((ext_vector_type(8))) _Float16;
using f16x4 = __attribute__((ext_vector_type(4))) _Float16;
using f32x4 = __attribute__((ext_vector_type(4))) float;

#define T_SEQ 2048
#define D_MODEL 512
#define NH 8
#define HD 64
#define NB 2
#define M_ROWS (NB * T_SEQ)   // 4096

// async global->LDS, 16B per lane. LDS dest must be wave-uniform base;
// HW adds lane*16. Source is per-lane.
#define GLOAD_LDS16(g, l)                                              \
  __builtin_amdgcn_global_load_lds(                                    \
      (const __attribute__((address_space(1))) void*)(g),              \
      (__attribute__((address_space(3))) void*)(l), 16, 0, 0)

// ---------------------------------------------------------------- converts
// fused: blocks [0,2048) convert x -> fp16; blocks [2048,3072) transpose-
// convert the 4 weight matrices and copy qkv biases.
__global__ __launch_bounds__(256) void cvt_all(
    const float* __restrict__ x, const float* __restrict__ wq,
    const float* __restrict__ wk, const float* __restrict__ wv,
    const float* __restrict__ wo, const float* __restrict__ bq,
    const float* __restrict__ bk, const float* __restrict__ bv,
    _Float16* __restrict__ xh, _Float16* __restrict__ wT,
    float* __restrict__ bias3) {
  int bid = blockIdx.x;
  int i = threadIdx.x;
  if (bid < 2048) {
    int idx = (bid * 256 + i) * 4;
    float4 v = *(const float4*)(x + idx);
    f16x4 h;
    h[0] = (_Float16)v.x; h[1] = (_Float16)v.y;
    h[2] = (_Float16)v.z; h[3] = (_Float16)v.w;
    *(f16x4*)(xh + idx) = h;
    return;
  }
  bid -= 2048;
  const int z = bid >> 8;
  const int by = (bid >> 4) & 15;
  const int bx = bid & 15;
  const float* w = z == 0 ? wq : z == 1 ? wk : z == 2 ? wv : wo;
  __shared__ float t[32][33];
  int r0 = by * 32, c0 = bx * 32;
#pragma unroll
  for (int p = 0; p < 4; ++p) {
    int e = p * 256 + i;
    int row = e >> 5, col = e & 31;
    t[row][col] = w[(size_t)(r0 + row) * D_MODEL + c0 + col];
  }
  __syncthreads();
  _Float16* o = wT + (size_t)z * D_MODEL * D_MODEL;
#pragma unroll
  for (int p = 0; p < 4; ++p) {
    int e = p * 256 + i;
    int orow = e >> 5, ocol = e & 31;
    o[(size_t)(c0 + orow) * D_MODEL + r0 + ocol] = (_Float16)t[ocol][orow];
  }
  if (bx == 0 && by == 0 && z < 3) {
    const float* bb = z == 0 ? bq : z == 1 ? bk : bv;
#pragma unroll
    for (int p = 0; p < 2; ++p)
      bias3[z * D_MODEL + p * 256 + i] = bb[p * 256 + i];
  }
}

// ---------------------------------------------------------------- GEMM
// C[m][n] = sum_k A[m][k] * Bt[n][k] + bias[n]
// 3-buffer 2-deep prefetch pipeline with counted vmcnt (T3+T4): stage(t+2)
// issued each iter; wait vmcnt(LPS) (one stage in flight) + raw s_barrier,
// never a full drain in the main loop. LDS XOR-swizzled (T2): gload_lds
// writes linearly; the SOURCE address is pre-swizzled (part ^= row&3) and
// reads apply the same XOR (involution, both-sides rule).
template <int OUT_F32, int BM>
__global__ __launch_bounds__(256) void gemm_bt(
    const _Float16* __restrict__ A, const _Float16* __restrict__ BtBase,
    const float* __restrict__ biasBase, void* outBase) {
  constexpr int BN = 128;
  constexpr int WROWS = (BM >= 128) ? 2 : 1;
  constexpr int WCOLS = 4 / WROWS;
  constexpr int MF = BM / WROWS / 16;
  constexpr int NF = BN / WCOLS / 16;
  constexpr int NT = D_MODEL / 32;            // 16 K-steps
  constexpr int LPS = BM / 64 + BN / 64;      // gload_lds per thread/stage
  const int z = blockIdx.z;
  const _Float16* Bt = BtBase + (size_t)z * D_MODEL * D_MODEL;
  const float* bias = biasBase + z * D_MODEL;
  const int m0 = blockIdx.y * BM;
  const int n0 = blockIdx.x * BN;
  __shared__ _Float16 At[3][BM * 32];
  __shared__ _Float16 Bts[3][BN * 32];
  const int tid = threadIdx.x;
  const int l = tid & 63;
  const int wv = tid >> 6;
  const int wm = wv / WCOLS, wn = wv % WCOLS;
  const int r16 = l & 15, g4 = l >> 4;
  f32x4 acc[MF][NF] = {};

  auto stage = [&](int bb, int k0) {
#pragma unroll
    for (int cc = 0; cc < BM / 64; ++cc) {
      int c = tid + cc * 256;
      int row = c >> 2, sp = (c & 3) ^ (row & 3);
      GLOAD_LDS16(&A[(size_t)(m0 + row) * D_MODEL + k0 + sp * 8],
                  &At[bb][(c - l) * 8]);
    }
#pragma unroll
    for (int cc = 0; cc < BN / 64; ++cc) {
      int c = tid + cc * 256;
      int row = c >> 2, sp = (c & 3) ^ (row & 3);
      GLOAD_LDS16(&Bt[(size_t)(n0 + row) * D_MODEL + k0 + sp * 8],
                  &Bts[bb][(c - l) * 8]);
    }
  };
  auto compute = [&](int bb) {
    f16x8 a[MF], b[NF];
#pragma unroll
    for (int mf = 0; mf < MF; ++mf) {
      int row = wm * (BM / WROWS) + mf * 16 + r16;
      a[mf] = *(const f16x8*)&At[bb][row * 32 + (g4 ^ (row & 3)) * 8];
    }
#pragma unroll
    for (int nf = 0; nf < NF; ++nf) {
      int row = wn * (BN / WCOLS) + nf * 16 + r16;
      b[nf] = *(const f16x8*)&Bts[bb][row * 32 + (g4 ^ (row & 3)) * 8];
    }
#pragma unroll
    for (int mf = 0; mf < MF; ++mf)
#pragma unroll
      for (int nf = 0; nf < NF; ++nf)
        acc[mf][nf] = __builtin_amdgcn_mfma_f32_16x16x32_f16(
            a[mf], b[nf], acc[mf][nf], 0, 0, 0);
  };

  // prologue: 2 tiles in flight
  stage(0, 0);
  stage(1, 32);
#pragma unroll
  for (int t = 0; t < NT; ++t) {
    if (t + 1 < NT)
      asm volatile("s_waitcnt vmcnt(%0)" ::"n"(LPS) : "memory");
    else
      asm volatile("s_waitcnt vmcnt(0)" ::: "memory");
    __builtin_amdgcn_s_barrier();
    compute(t % 3);
    if (t + 2 < NT) stage((t + 2) % 3, (t + 2) * 32);
  }

#pragma unroll
  for (int mf = 0; mf < MF; ++mf) {
#pragma unroll
    for (int nf = 0; nf < NF; ++nf) {
      int col = n0 + wn * (BN / WCOLS) + nf * 16 + r16;
      float bs = bias[col];
#pragma unroll
      for (int r = 0; r < 4; ++r) {
        int rowi = m0 + wm * (BM / WROWS) + mf * 16 + g4 * 4 + r;
        float v = acc[mf][nf][r] + bs;
        if (OUT_F32)
          ((float*)outBase)[(size_t)rowi * D_MODEL + col] = v;
        else
          ((_Float16*)outBase)[(size_t)z * M_ROWS * D_MODEL +
                               (size_t)rowi * D_MODEL + col] = (_Float16)v;
      }
    }
  }
}

// ---------------------------------------------------------------- attention
// one block per (b, h, 64-query tile). keys j=0..127 map to t = t0-32+j.
// window for query ql: j in [ql, ql+64]. out-of-sequence keys are zero
// (score 0 participates in softmax denom = reference zero-pad semantics).
// Q in registers; K XOR-swizzled via pre-swizzled source; Vt/Ps padded 136.
__global__ __launch_bounds__(256) void local_attn(
    const _Float16* __restrict__ Q, const _Float16* __restrict__ K,
    const _Float16* __restrict__ V, _Float16* __restrict__ att) {
  const int t0 = blockIdx.x * 64;
  const int h = blockIdx.y;
  const int b = blockIdx.z;
  const int k0 = t0 - 32;
  __shared__ _Float16 Ks[128 * 64];
  __shared__ _Float16 Vt[64 * 136];
  __shared__ _Float16 Ps[64 * 136];
  const int tid = threadIdx.x;
  const int l = tid & 63;
  const int wv = tid >> 6;
  const int r16 = l & 15, g4 = l >> 4;
  const size_t colbase = (size_t)h * HD;
  // Q fragments straight to registers
  f16x8 qf[2];
#pragma unroll
  for (int kk = 0; kk < 2; ++kk)
    qf[kk] = *(const f16x8*)&Q[(size_t)(b * T_SEQ + t0 + wv * 16 + r16) *
                                   D_MODEL + colbase + kk * 32 + g4 * 8];
  // stage K (128 rows): interior DMA (swizzled source), edge reg path
  const bool interior = (k0 >= 0) && (k0 + 128 <= T_SEQ);
  if (interior) {
#pragma unroll
    for (int cc = 0; cc < 4; ++cc) {
      int c = tid + cc * 256;
      int row = c >> 3, part = c & 7;
      int sp = part ^ (row & 7);
      GLOAD_LDS16(
          &K[(size_t)(b * T_SEQ + k0 + row) * D_MODEL + colbase + sp * 8],
          &Ks[(c - l) * 8]);
    }
  } else {
#pragma unroll
    for (int cc = 0; cc < 4; ++cc) {
      int c = tid + cc * 256;
      int row = c >> 3, part = c & 7;
      int t = k0 + row;
      f16x8 v = {};
      if (t >= 0 && t < T_SEQ)
        v = *(const f16x8*)&K[(size_t)(b * T_SEQ + t) * D_MODEL + colbase +
                              part * 8];
      *(f16x8*)&Ks[row * 64 + (part ^ (row & 7)) * 8] = v;
    }
  }
  // stage V transposed: Vt[dd][key], padded stride 136
#pragma unroll
  for (int cc = 0; cc < 4; ++cc) {
    int c = tid + cc * 256;
    int row = c >> 3, part = c & 7;
    int t = k0 + row;
    f16x8 v = {};
    if (t >= 0 && t < T_SEQ)
      v = *(const f16x8*)&V[(size_t)(b * T_SEQ + t) * D_MODEL + colbase +
                            part * 8];
#pragma unroll
    for (int j = 0; j < 8; ++j) Vt[(part * 8 + j) * 136 + row] = v[j];
  }
  __syncthreads();
  // S = Q K^T : wave wv owns query rows [wv*16, wv*16+16), all 128 keys
  f32x4 s[8] = {};
#pragma unroll
  for (int kk = 0; kk < 2; ++kk) {
    int p = kk * 4 + g4;
#pragma unroll
    for (int nf = 0; nf < 8; ++nf) {
      f16x8 bb =
          *(const f16x8*)&Ks[(nf * 16 + r16) * 64 + (p ^ (r16 & 7)) * 8];
      s[nf] =
          __builtin_amdgcn_mfma_f32_16x16x32_f16(qf[kk], bb, s[nf], 0, 0, 0);
    }
  }
  // softmax: lane's rows ql = wv*16 + g4*4 + r ; cols j = nf*16 + r16
#pragma unroll
  for (int r = 0; r < 4; ++r) {
    int ql = wv * 16 + g4 * 4 + r;
    float vals[8];
    float m = -1e30f;
#pragma unroll
    for (int nf = 0; nf < 8; ++nf) {
      int j = nf * 16 + r16;
      bool in = (j >= ql) && (j <= ql + 64);
      float sv = in ? s[nf][r] * 0.125f : -1e30f;
      vals[nf] = sv;
      m = fmaxf(m, sv);
    }
#pragma unroll
    for (int off = 1; off < 16; off <<= 1) m = fmaxf(m, __shfl_xor(m, off, 64));
    float e[8];
    float sum = 0.f;
#pragma unroll
    for (int nf = 0; nf < 8; ++nf) {
      float ev = (vals[nf] > -1e29f) ? __expf(vals[nf] - m) : 0.f;
      e[nf] = ev;
      sum += ev;
    }
#pragma unroll
    for (int off = 1; off < 16; off <<= 1) sum += __shfl_xor(sum, off, 64);
    float inv = 1.f / sum;
#pragma unroll
    for (int nf = 0; nf < 8; ++nf)
      Ps[ql * 136 + nf * 16 + r16] = (_Float16)(e[nf] * inv);
  }
  __syncthreads();
  // O = P V : wave wv owns query rows [wv*16, wv*16+16), dims 0..63
  f32x4 o[4] = {};
#pragma unroll
  for (int kk = 0; kk < 4; ++kk) {
    f16x8 a = *(const f16x8*)&Ps[(wv * 16 + r16) * 136 + kk * 32 + g4 * 8];
#pragma unroll
    for (int nf = 0; nf < 4; ++nf) {
      f16x8 bb = *(const f16x8*)&Vt[(nf * 16 + r16) * 136 + kk * 32 + g4 * 8];
      o[nf] = __builtin_amdgcn_mfma_f32_16x16x32_f16(a, bb, o[nf], 0, 0, 0);
    }
  }
#pragma unroll
  for (int nf = 0; nf < 4; ++nf)
#pragma unroll
    for (int r = 0; r < 4; ++r) {
      int row = t0 + wv * 16 + g4 * 4 + r;
      int col = nf * 16 + r16;
      att[(size_t)(b * T_SEQ + row) * D_MODEL + colbase + col] =
          (_Float16)o[nf][r];
    }
}

// ---------------------------------------------------------------- launch
extern "C" void kernel_launch(void* const* d_in, const int* in_sizes, int n_in,
                              void* d_out, int out_size, void* d_ws,
                              size_t ws_size, hipStream_t stream) {
  const float* x = (const float*)d_in[0];
  const float* wq = (const float*)d_in[1];
  const float* bq = (const float*)d_in[2];
  const float* wk = (const float*)d_in[3];
  const float* bk = (const float*)d_in[4];
  const float* wv = (const float*)d_in[5];
  const float* bv = (const float*)d_in[6];
  const float* wo = (const float*)d_in[7];
  const float* bo = (const float*)d_in[8];

  char* ws = (char*)d_ws;
  _Float16* xh = (_Float16*)(ws);                    // 4 MB (reused as att)
  _Float16* wT = (_Float16*)(ws + (4 << 20));        // 2 MB
  float* bias3 = (float*)(ws + (6 << 20));           // 6 KB
  _Float16* QKV = (_Float16*)(ws + (6 << 20) + (64 << 10));  // 12 MB
  _Float16* att = xh;                                // reuse x-half region

  cvt_all<<<3072, 256, 0, stream>>>(x, wq, wk, wv, wo, bq, bk, bv, xh, wT,
                                    bias3);
  gemm_bt<0, 128><<<dim3(4, 32, 3), 256, 0, stream>>>(xh, wT, bias3, QKV);
  const _Float16* Qm = QKV;
  const _Float16* Km = QKV + (size_t)M_ROWS * D_MODEL;
  const _Float16* Vm = Km + (size_t)M_ROWS * D_MODEL;
  local_attn<<<dim3(32, 8, 2), 256, 0, stream>>>(Qm, Km, Vm, att);
  gemm_bt<1, 64><<<dim3(4, 64, 1), 256, 0, stream>>>(
      att, wT + (size_t)3 * D_MODEL * D_MODEL, bo, d_out);
}